// Round 6
// baseline (183.413 us; speedup 1.0000x reference)
//
#include <hip/hip_runtime.h>

typedef unsigned int uint;
typedef unsigned short ushort_t;

// Problem constants
#define CN 32          // channels
#define HW 4096        // H*W
#define KDIM 288       // C*9
#define PDIM 8192      // N*HW
#define NB 2           // batch

typedef __attribute__((ext_vector_type(8))) short bf16x8;
typedef __attribute__((ext_vector_type(4))) float f32x4;

static __device__ __forceinline__ ushort_t f2bf(float f) {
    uint u = __float_as_uint(f);
    uint r = (u + 0x7fffu + ((u >> 16) & 1u)) >> 16;
    return (ushort_t)r;
}

static __device__ __forceinline__ float fast_tanh(float v) {
    // tanh(v) = 1 - 2/(1+e^{2v}); exact at +-inf, ~1e-7 rel err
    float e = __expf(2.0f * v);
    return 1.0f - 2.0f / (e + 1.0f);
}

// k-permutation within each 32-k group: 16B chunk slot s holds logical
// k = {g*32 + 4s..4s+3, g*32 + 16+4s..16+4s+3}. Lane kg's whole MFMA
// fragment (k = kg*4+j, 16+kg*4+j) is then ONE contiguous 16B global load.

// ---------------- out zeroing (fused kernel accumulates via atomics) --------
__global__ __launch_bounds__(256) void zero_out(float4* __restrict__ out) {
    out[blockIdx.x * 256 + threadIdx.x] = make_float4(0.f, 0.f, 0.f, 0.f);
}

// ---------------- conv1 + relu: x (N,32,64,64) -> h ----------------
__global__ __launch_bounds__(256) void conv1_relu(
    const float* __restrict__ x, const float* __restrict__ w1,
    float* __restrict__ hout)
{
    int idx = blockIdx.x * 256 + threadIdx.x;   // N*C*HW = 262144 total
    int w  = idx & 63;
    int hh = (idx >> 6) & 63;
    int c  = (idx >> 12) & 31;
    int n  = idx >> 17;
    const float* wp = w1 + c * KDIM;
    float acc = 0.f;
    for (int ci = 0; ci < CN; ci++) {
        const float* xp = x + (((size_t)n * CN + ci) << 12);
        #pragma unroll
        for (int kh = 0; kh < 3; kh++) {
            int y = hh + kh - 1;
            if ((unsigned)y >= 64u) continue;
            #pragma unroll
            for (int kw = 0; kw < 3; kw++) {
                int xw = w + kw - 1;
                if ((unsigned)xw >= 64u) continue;
                acc = fmaf(xp[(y << 6) + xw], wp[ci * 9 + kh * 3 + kw], acc);
            }
        }
    }
    hout[idx] = fmaxf(acc, 0.f);
}

// ---------------- w2 fp32 -> bf16, k-PERMUTED rows [9216][288] ----------------
__global__ __launch_bounds__(256) void w2_to_bf16_perm(
    const float* __restrict__ in, ushort_t* __restrict__ out)
{
    int idx = blockIdx.x * 256 + threadIdx.x;   // chunk id, 9216*36 total
    int row = idx / 36;                          // 36 chunks per 288-k row
    int cw  = idx - row * 36;
    int g = cw >> 2, s = cw & 3;
    const float* base = in + (size_t)row * KDIM + g * 32;
    float4 lo = *(const float4*)(base + s * 4);
    float4 hi = *(const float4*)(base + 16 + s * 4);
    alignas(16) ushort_t o[8] = {f2bf(lo.x), f2bf(lo.y), f2bf(lo.z), f2bf(lo.w),
                                 f2bf(hi.x), f2bf(hi.y), f2bf(hi.z), f2bf(hi.w)};
    *(uint4*)(out + (size_t)idx * 8) = *(const uint4*)o;
}

// ---------------- im2col of h, P-MAJOR k-PERMUTED bf16: Bm[p][kperm] ----------------
__global__ __launch_bounds__(256) void im2col_bf16_perm(
    const float* __restrict__ h, ushort_t* __restrict__ Bm)
{
    int idx = blockIdx.x * 256 + threadIdx.x;   // PDIM*KDIM
    int kp = idx % KDIM;
    int p  = idx / KDIM;
    // invert permutation: logical k for permuted position kp
    int pos = kp & 31, s = pos >> 3, j = pos & 7;
    int ko = (j < 4) ? (s * 4 + j) : (16 + s * 4 + j - 4);
    int k  = (kp & ~31) + ko;
    int n  = p >> 12;
    int sp = p & 4095;
    int hh = sp >> 6;
    int w  = sp & 63;
    int ci = k / 9;
    int kk = k - ci * 9;
    int kh = kk / 3;
    int kw = kk - kh * 3;
    int y  = hh + kh - 1;
    int xw = w + kw - 1;
    float v = 0.f;
    if ((unsigned)y < 64u && (unsigned)xw < 64u)
        v = h[(((size_t)n * CN + ci) << 12) + (y << 6) + xw];
    Bm[idx] = f2bf(v);
}

// ---------------- fused: direct-reg MFMA GEMM + tanh + apply ----------------
// Semantics (R5-proven):
//   W(co,ci,t) = tanh(rst[(co*32+ci)*9 + (t>>12), n*4096 + (t&4095)]),
//   out[n,co,sp] = sum_{ci,kk} W(co,ci, t=sp*9+kk) * x[n,ci,nbr(sp,kk)].
// Block = (tw, cg, n) via XCD-swizzled flat blockIdx. t-window [T0,T0+128).
// NO LDS staging: fragments load straight global->VGPR (16B/lane, k-permuted
// layout makes them contiguous; 4 kg lanes x 16B = full 64B lines). A/B are
// L1/L2-resident; K-loop has zero barriers.
__global__ __launch_bounds__(256) void fused_gemm_apply(
    const ushort_t* __restrict__ A, const ushort_t* __restrict__ B,
    const float* __restrict__ x, float* __restrict__ out)
{
    __shared__ float vred[4][128];      // per-(g, t_local) ci-summed values

    int tid = threadIdx.x;
    // bijective XCD swizzle: 4608 blocks = 8 XCDs x 576; consecutive sb share
    // (cg,n) -> per-XCD L2 working set = 2 A-panels + one n's B slice (~3.7MB)
    int bid = blockIdx.x;
    int sb  = (bid & 7) * 576 + (bid >> 3);
    int tw  = sb % 288;
    int cg  = (sb / 288) & 7;
    int n   = sb / 2304;

    int lane = tid & 63, wv = tid >> 6;
    int wm = wv >> 1, wn = wv & 1;      // 2x2 wave grid: wm->m, wn->t
    int i16 = lane & 15, kg = lane >> 4;

    int T0 = tw * 128;
    int c8 = T0 >> 12;                  // block-constant rst sub-channel
    int q0 = T0 & 4095;                 // contiguous B column window start

    // per-lane fragment base pointers (k-permuted: slot kg = 16B at kg*8)
    const ushort_t* pA[4];
    const ushort_t* pB[4];
    #pragma unroll
    for (int mf = 0; mf < 4; mf++) {
        int rowA = wm * 64 + mf * 16 + i16;                 // 0..127
        int arow = (cg * 4 + (rowA >> 5)) * KDIM + (rowA & 31) * 9 + c8;
        pA[mf] = A + (size_t)arow * KDIM + kg * 8;
    }
    #pragma unroll
    for (int nf = 0; nf < 4; nf++) {
        int rowB = (n << 12) + q0 + wn * 64 + nf * 16 + i16;
        pB[nf] = B + (size_t)rowB * KDIM + kg * 8;
    }

    f32x4 acc[4][4] = {};

    #pragma unroll
    for (int ks = 0; ks < 9; ks++) {
        bf16x8 af[4], bfr[4];
        #pragma unroll
        for (int mf = 0; mf < 4; mf++)
            af[mf] = *(const bf16x8*)(pA[mf] + ks * 32);
        #pragma unroll
        for (int nf = 0; nf < 4; nf++)
            bfr[nf] = *(const bf16x8*)(pB[nf] + ks * 32);
        #pragma unroll
        for (int mf = 0; mf < 4; mf++)
            #pragma unroll
            for (int nf = 0; nf < 4; nf++)
                acc[mf][nf] = __builtin_amdgcn_mfma_f32_16x16x32_bf16(
                    af[mf], bfr[nf], acc[mf][nf], 0, 0, 0);
    }

    // ---- epilogue: tanh, x-weighted, reduce over ci (m) then kk (t) ----
    // D layout: m_local = wm*64 + mf*16 + kg*4 + r, t_local = wn*64 + nf*16 + i16
    // ci = (mf*16 + kg*4 + r) & 31; g = 2*wm + (mf>>1)   (R5-proven)
    const float* xn = x + (((size_t)n * CN) << 12);
    #pragma unroll
    for (int nf = 0; nf < 4; nf++) {
        int t  = T0 + wn * 64 + nf * 16 + i16;
        uint sp = ((uint)t * 58255u) >> 19;       // t/9, exact for t < 74898
        int kk = t - (int)sp * 9;
        int kh = (kk * 11) >> 5;                  // kk/3
        int kw = kk - kh * 3;
        int y  = (int)(sp >> 6) + kh - 1;
        int xw = (int)(sp & 63) + kw - 1;
        bool ok = ((unsigned)y < 64u) && ((unsigned)xw < 64u);
        int poff = (y << 6) + xw;
        float xa[4], xb[4];
        #pragma unroll
        for (int r = 0; r < 4; r++) {
            int cia = kg * 4 + r;
            xa[r] = ok ? xn[((size_t)cia << 12) + poff] : 0.f;
            xb[r] = ok ? xn[((size_t)(cia + 16) << 12) + poff] : 0.f;
        }
        float s0 = 0.f, s1 = 0.f;
        #pragma unroll
        for (int r = 0; r < 4; r++) {
            s0 = fmaf(fast_tanh(acc[0][nf][r]), xa[r], s0);
            s0 = fmaf(fast_tanh(acc[1][nf][r]), xb[r], s0);
            s1 = fmaf(fast_tanh(acc[2][nf][r]), xa[r], s1);
            s1 = fmaf(fast_tanh(acc[3][nf][r]), xb[r], s1);
        }
        // sum the 4 kg groups (lanes l, l^16, l^32, l^48 share t) -> all 32 ci
        s0 += __shfl_xor(s0, 16); s0 += __shfl_xor(s0, 32);
        s1 += __shfl_xor(s1, 16); s1 += __shfl_xor(s1, 32);
        if (kg == 0) {
            vred[2 * wm + 0][wn * 64 + nf * 16 + i16] = s0;
            vred[2 * wm + 1][wn * 64 + nf * 16 + i16] = s1;
        }
    }
    __syncthreads();

    // ---- fold 9 t's per pixel, atomicAdd (2-way only on window boundaries) ----
    if (tid < 64) {
        int g  = tid >> 4, bi = tid & 15;
        uint spA = ((uint)T0 * 58255u) >> 19;
        int sp = (int)spA + bi;
        int lo = sp * 9;     if (lo < T0) lo = T0;
        int hi = sp * 9 + 9; if (hi > T0 + 128) hi = T0 + 128;
        if (lo < hi) {
            float s = 0.f;
            for (int t = lo; t < hi; t++) s += vred[g][t - T0];
            atomicAdd(&out[(((size_t)n * CN + cg * 4 + g) << 12) + sp], s);
        }
    }
}

extern "C" void kernel_launch(void* const* d_in, const int* in_sizes, int n_in,
                              void* d_out, int out_size, void* d_ws, size_t ws_size,
                              hipStream_t stream) {
    const float* x  = (const float*)d_in[0];
    const float* w1 = (const float*)d_in[1];
    const float* w2 = (const float*)d_in[2];
    float* out = (float*)d_out;
    char* ws = (char*)d_ws;

    float*    hbuf  = (float*)ws;                       // 1 MiB
    ushort_t* Bm_bf = (ushort_t*)(ws + 1048576u);       // 8192*288*2 = 4718592 B
    ushort_t* A_bf  = (ushort_t*)(ws + 5767168u);       // 9216*288*2 = 5308416 B

    hipLaunchKernelGGL(zero_out, dim3(256), dim3(256), 0, stream, (float4*)out);
    hipLaunchKernelGGL(conv1_relu, dim3(1024), dim3(256), 0, stream, x, w1, hbuf);
    hipLaunchKernelGGL(w2_to_bf16_perm, dim3(1296), dim3(256), 0, stream, w2, A_bf);
    hipLaunchKernelGGL(im2col_bf16_perm, dim3((PDIM * KDIM) / 256), dim3(256), 0,
                       stream, hbuf, Bm_bf);
    hipLaunchKernelGGL(fused_gemm_apply, dim3(4608), dim3(256), 0, stream,
                       A_bf, Bm_bf, x, out);
}

// Round 8
// 151.878 us; speedup vs baseline: 1.2076x; 1.2076x over previous
//
#include <hip/hip_runtime.h>

typedef unsigned int uint;
typedef unsigned short ushort_t;

// Problem constants
#define CN 32          // channels
#define HW 4096        // H*W
#define KDIM 288       // C*9
#define PDIM 8192      // N*HW
#define NB 2           // batch

typedef __attribute__((ext_vector_type(8))) short bf16x8;
typedef __attribute__((ext_vector_type(4))) float f32x4;

static __device__ __forceinline__ ushort_t f2bf(float f) {
    uint u = __float_as_uint(f);
    uint r = (u + 0x7fffu + ((u >> 16) & 1u)) >> 16;
    return (ushort_t)r;
}

static __device__ __forceinline__ void gl_lds16(const void* g, void* l) {
    __builtin_amdgcn_global_load_lds(
        (const __attribute__((address_space(1))) unsigned int*)g,
        (__attribute__((address_space(3))) unsigned int*)l, 16, 0, 0);
}

static __device__ __forceinline__ float fast_tanh(float v) {
    // tanh(v) = 1 - 2/(1+e^{2v}); exact at +-inf, ~1e-7 rel err
    float e = __expf(2.0f * v);
    return 1.0f - 2.0f / (e + 1.0f);
}

// k-permutation within each 32-k group: 16B chunk slot s holds logical
// k = {g*32 + 4s..4s+3, g*32 + 16+4s..16+4s+3}. Lane kg's whole MFMA
// fragment (k = kg*4+j, 16+kg*4+j) is then ONE contiguous 16B LDS chunk.

// ---------------- conv1 + relu: x (N,32,64,64) -> h ----------------
__global__ __launch_bounds__(256) void conv1_relu(
    const float* __restrict__ x, const float* __restrict__ w1,
    float* __restrict__ hout)
{
    int idx = blockIdx.x * 256 + threadIdx.x;   // N*C*HW = 262144 total
    int w  = idx & 63;
    int hh = (idx >> 6) & 63;
    int c  = (idx >> 12) & 31;
    int n  = idx >> 17;
    const float* wp = w1 + c * KDIM;
    float acc = 0.f;
    for (int ci = 0; ci < CN; ci++) {
        const float* xp = x + (((size_t)n * CN + ci) << 12);
        #pragma unroll
        for (int kh = 0; kh < 3; kh++) {
            int y = hh + kh - 1;
            if ((unsigned)y >= 64u) continue;
            #pragma unroll
            for (int kw = 0; kw < 3; kw++) {
                int xw = w + kw - 1;
                if ((unsigned)xw >= 64u) continue;
                acc = fmaf(xp[(y << 6) + xw], wp[ci * 9 + kh * 3 + kw], acc);
            }
        }
    }
    hout[idx] = fmaxf(acc, 0.f);
}

// -------- w2 fp32 -> bf16 k-PERMUTED [9216][288]; also zeroes out --------
// out is 262144 floats = 65536 float4 (N*C*H*W = 2*32*64*64). BOUND = 65536.
__global__ __launch_bounds__(256) void w2_to_bf16_perm(
    const float* __restrict__ in, ushort_t* __restrict__ out_bf,
    float4* __restrict__ out_zero)
{
    int idx = blockIdx.x * 256 + threadIdx.x;   // chunk id, 9216*36 total
    if (idx < 65536)
        out_zero[idx] = make_float4(0.f, 0.f, 0.f, 0.f);
    int row = idx / 36;                          // 36 chunks per 288-k row
    int cw  = idx - row * 36;
    int g = cw >> 2, s = cw & 3;
    const float* base = in + (size_t)row * KDIM + g * 32;
    float4 lo = *(const float4*)(base + s * 4);
    float4 hi = *(const float4*)(base + 16 + s * 4);
    alignas(16) ushort_t o[8] = {f2bf(lo.x), f2bf(lo.y), f2bf(lo.z), f2bf(lo.w),
                                 f2bf(hi.x), f2bf(hi.y), f2bf(hi.z), f2bf(hi.w)};
    *(uint4*)(out_bf + (size_t)idx * 8) = *(const uint4*)o;
}

// ---------------- im2col of h, P-MAJOR k-PERMUTED bf16: Bm[p][kperm] ----------------
__global__ __launch_bounds__(256) void im2col_bf16_perm(
    const float* __restrict__ h, ushort_t* __restrict__ Bm)
{
    int idx = blockIdx.x * 256 + threadIdx.x;   // PDIM*KDIM
    int kp = idx % KDIM;
    int p  = idx / KDIM;
    // invert permutation: logical k for permuted position kp
    int pos = kp & 31, s = pos >> 3, j = pos & 7;
    int ko = (j < 4) ? (s * 4 + j) : (16 + s * 4 + j - 4);
    int k  = (kp & ~31) + ko;
    int n  = p >> 12;
    int sp = p & 4095;
    int hh = sp >> 6;
    int w  = sp & 63;
    int ci = k / 9;
    int kk = k - ci * 9;
    int kh = kk / 3;
    int kw = kk - kh * 3;
    int y  = hh + kh - 1;
    int xw = w + kw - 1;
    float v = 0.f;
    if ((unsigned)y < 64u && (unsigned)xw < 64u)
        v = h[(((size_t)n * CN + ci) << 12) + (y << 6) + xw];
    Bm[idx] = f2bf(v);
}

// ---------------- fused: MFMA GEMM + tanh + apply (LDS dbuf pipeline) -------
// Semantics (R5-proven):
//   W(co,ci,t) = tanh(rst[(co*32+ci)*9 + (t>>12), n*4096 + (t&4095)]),
//   out[n,co,sp] = sum_{ci,kk} W(co,ci, t=sp*9+kk) * x[n,ci,nbr(sp,kk)].
// Block = (tw, cg, n) via XCD-swizzled flat blockIdx (R6-proven locality).
// K-loop: double-buffered LDS; STAGE(next) issued BEFORE ds_read+MFMA(cur);
// one __syncthreads per step (vmcnt(0) drain lands after compute).
__global__ __launch_bounds__(256) void fused_gemm_apply(
    const ushort_t* __restrict__ A, const ushort_t* __restrict__ B,
    const float* __restrict__ x, float* __restrict__ out)
{
    __shared__ ushort_t AL[2][128 * 32];   // 2 x 8 KiB
    __shared__ ushort_t BL[2][128 * 32];   // 2 x 8 KiB
    __shared__ float vred[4][128];         // per-(g, t_local) ci-summed values

    int tid = threadIdx.x;
    // bijective XCD swizzle: 4608 = 8 XCDs x 576; consecutive sb share (cg,n)
    int bid = blockIdx.x;
    int sb  = (bid & 7) * 576 + (bid >> 3);
    int tw  = sb % 288;
    int cg  = (sb / 288) & 7;
    int n   = sb / 2304;

    int lane = tid & 63, wv = tid >> 6;
    int wm = wv >> 1, wn = wv & 1;      // 2x2 wave grid: wm->m, wn->t
    int i16 = lane & 15, kg = lane >> 4;

    int T0 = tw * 128;
    int c8 = T0 >> 12;                  // block-constant rst sub-channel
    int q0 = T0 & 4095;                 // contiguous B column window start

    // staging chunk geometry (2 chunks of A + 2 of B per thread per K-step)
    int c_0 = tid, c_1 = 256 + tid;
    int row0 = c_0 >> 2, row1 = c_1 >> 2;
    int k8_0 = (((c_0 & 3) ^ ((c_0 >> 3) & 3)) << 3);  // pre-swizzled source
    int k8_1 = (((c_1 & 3) ^ ((c_1 >> 3) & 3)) << 3);
    const ushort_t* srcA0 = A +
        (size_t)((cg * 4 + (row0 >> 5)) * KDIM + (row0 & 31) * 9 + c8) * KDIM + k8_0;
    const ushort_t* srcA1 = A +
        (size_t)((cg * 4 + (row1 >> 5)) * KDIM + (row1 & 31) * 9 + c8) * KDIM + k8_1;
    const ushort_t* srcB0 = B + (size_t)((n << 12) + q0 + row0) * KDIM + k8_0;
    const ushort_t* srcB1 = B + (size_t)((n << 12) + q0 + row1) * KDIM + k8_1;
    int dst0 = wv * 512, dst1 = 2048 + wv * 512;

    f32x4 acc[4][4] = {};

    // prologue: stage K-tile 0 into buffer 0
    gl_lds16(srcA0, &AL[0][dst0]);
    gl_lds16(srcA1, &AL[0][dst1]);
    gl_lds16(srcB0, &BL[0][dst0]);
    gl_lds16(srcB1, &BL[0][dst1]);
    __syncthreads();

    #pragma unroll
    for (int ks = 0; ks < 9; ks++) {
        int cur = ks & 1;
        // stage next K-tile first (latency hides under ds_read + MFMA)
        if (ks < 8) {
            int k0 = (ks + 1) * 32;
            gl_lds16(srcA0 + k0, &AL[cur ^ 1][dst0]);
            gl_lds16(srcA1 + k0, &AL[cur ^ 1][dst1]);
            gl_lds16(srcB0 + k0, &BL[cur ^ 1][dst0]);
            gl_lds16(srcB1 + k0, &BL[cur ^ 1][dst1]);
        }

        bf16x8 af[4], bfr[4];
        #pragma unroll
        for (int mf = 0; mf < 4; mf++) {
            int row = wm * 64 + mf * 16 + i16;
            af[mf] = *(const bf16x8*)
                &AL[cur][row * 32 + ((kg ^ ((row >> 1) & 3)) << 3)];
        }
        #pragma unroll
        for (int nf = 0; nf < 4; nf++) {
            int row = wn * 64 + nf * 16 + i16;
            bfr[nf] = *(const bf16x8*)
                &BL[cur][row * 32 + ((kg ^ ((row >> 1) & 3)) << 3)];
        }
        #pragma unroll
        for (int mf = 0; mf < 4; mf++)
            #pragma unroll
            for (int nf = 0; nf < 4; nf++)
                acc[mf][nf] = __builtin_amdgcn_mfma_f32_16x16x32_bf16(
                    af[mf], bfr[nf], acc[mf][nf], 0, 0, 0);
        __syncthreads();   // drains vmcnt(0): next buffer ready for ks+1
    }

    // ---- epilogue: tanh, x-weighted, reduce over ci (m) then kk (t) ----
    // D layout: m_local = wm*64 + mf*16 + kg*4 + r, t_local = wn*64 + nf*16 + i16
    // ci = (mf*16 + kg*4 + r) & 31; g = 2*wm + (mf>>1)   (R5-proven)
    const float* xn = x + (((size_t)n * CN) << 12);
    #pragma unroll
    for (int nf = 0; nf < 4; nf++) {
        int t  = T0 + wn * 64 + nf * 16 + i16;
        uint sp = ((uint)t * 58255u) >> 19;       // t/9, exact for t < 74898
        int kk = t - (int)sp * 9;
        int kh = (kk * 11) >> 5;                  // kk/3
        int kw = kk - kh * 3;
        int y  = (int)(sp >> 6) + kh - 1;
        int xw = (int)(sp & 63) + kw - 1;
        bool ok = ((unsigned)y < 64u) && ((unsigned)xw < 64u);
        int poff = (y << 6) + xw;
        float xa[4], xb[4];
        #pragma unroll
        for (int r = 0; r < 4; r++) {
            int cia = kg * 4 + r;
            xa[r] = ok ? xn[((size_t)cia << 12) + poff] : 0.f;
            xb[r] = ok ? xn[((size_t)(cia + 16) << 12) + poff] : 0.f;
        }
        float s0 = 0.f, s1 = 0.f;
        #pragma unroll
        for (int r = 0; r < 4; r++) {
            s0 = fmaf(fast_tanh(acc[0][nf][r]), xa[r], s0);
            s0 = fmaf(fast_tanh(acc[1][nf][r]), xb[r], s0);
            s1 = fmaf(fast_tanh(acc[2][nf][r]), xa[r], s1);
            s1 = fmaf(fast_tanh(acc[3][nf][r]), xb[r], s1);
        }
        // sum the 4 kg groups (lanes l, l^16, l^32, l^48 share t) -> all 32 ci
        s0 += __shfl_xor(s0, 16); s0 += __shfl_xor(s0, 32);
        s1 += __shfl_xor(s1, 16); s1 += __shfl_xor(s1, 32);
        if (kg == 0) {
            vred[2 * wm + 0][wn * 64 + nf * 16 + i16] = s0;
            vred[2 * wm + 1][wn * 64 + nf * 16 + i16] = s1;
        }
    }
    __syncthreads();

    // ---- fold 9 t's per pixel, atomicAdd (2-way only on window boundaries) ----
    if (tid < 64) {
        int g  = tid >> 4, bi = tid & 15;
        uint spA = ((uint)T0 * 58255u) >> 19;
        int sp = (int)spA + bi;
        int lo = sp * 9;     if (lo < T0) lo = T0;
        int hi = sp * 9 + 9; if (hi > T0 + 128) hi = T0 + 128;
        if (lo < hi) {
            float s = 0.f;
            for (int t = lo; t < hi; t++) s += vred[g][t - T0];
            atomicAdd(&out[(((size_t)n * CN + cg * 4 + g) << 12) + sp], s);
        }
    }
}

extern "C" void kernel_launch(void* const* d_in, const int* in_sizes, int n_in,
                              void* d_out, int out_size, void* d_ws, size_t ws_size,
                              hipStream_t stream) {
    const float* x  = (const float*)d_in[0];
    const float* w1 = (const float*)d_in[1];
    const float* w2 = (const float*)d_in[2];
    float* out = (float*)d_out;
    char* ws = (char*)d_ws;

    float*    hbuf  = (float*)ws;                       // 1 MiB
    ushort_t* Bm_bf = (ushort_t*)(ws + 1048576u);       // 8192*288*2 = 4718592 B
    ushort_t* A_bf  = (ushort_t*)(ws + 5767168u);       // 9216*288*2 = 5308416 B

    hipLaunchKernelGGL(conv1_relu, dim3(1024), dim3(256), 0, stream, x, w1, hbuf);
    hipLaunchKernelGGL(w2_to_bf16_perm, dim3(1296), dim3(256), 0, stream,
                       w2, A_bf, (float4*)out);
    hipLaunchKernelGGL(im2col_bf16_perm, dim3((PDIM * KDIM) / 256), dim3(256), 0,
                       stream, hbuf, Bm_bf);
    hipLaunchKernelGGL(fused_gemm_apply, dim3(4608), dim3(256), 0, stream,
                       A_bf, Bm_bf, x, out);
}

// Round 10
// 146.628 us; speedup vs baseline: 1.2509x; 1.0358x over previous
//
#include <hip/hip_runtime.h>

typedef unsigned int uint;
typedef unsigned short ushort_t;

// Problem constants
#define CN 32          // channels
#define HW 4096        // H*W
#define KDIM 288       // C*9
#define PDIM 8192      // N*HW
#define NB 2           // batch

typedef __attribute__((ext_vector_type(8))) short bf16x8;
typedef __attribute__((ext_vector_type(4))) float f32x4;

static __device__ __forceinline__ ushort_t f2bf(float f) {
    uint u = __float_as_uint(f);
    uint r = (u + 0x7fffu + ((u >> 16) & 1u)) >> 16;
    return (ushort_t)r;
}

static __device__ __forceinline__ void gl_lds16(const void* g, void* l) {
    __builtin_amdgcn_global_load_lds(
        (const __attribute__((address_space(1))) unsigned int*)g,
        (__attribute__((address_space(3))) unsigned int*)l, 16, 0, 0);
}

static __device__ __forceinline__ float fast_tanh(float v) {
    // tanh(v) = 1 - 2/(1+e^{2v}); exact at +-inf, ~1e-7 rel err
    float e = __expf(2.0f * v);
    return 1.0f - 2.0f / (e + 1.0f);
}

// k-permutation within each 32-k group: 16B chunk slot s holds logical
// k = {g*32 + 4s..4s+3, g*32 + 16+4s..16+4s+3}. Lane kg's whole MFMA
// fragment (k = kg*4+j, 16+kg*4+j) is then ONE contiguous 16B LDS chunk.

// ---------------- conv1 + relu: x (N,32,64,64) -> h ----------------
__global__ __launch_bounds__(256) void conv1_relu(
    const float* __restrict__ x, const float* __restrict__ w1,
    float* __restrict__ hout)
{
    int idx = blockIdx.x * 256 + threadIdx.x;   // N*C*HW = 262144 total
    int w  = idx & 63;
    int hh = (idx >> 6) & 63;
    int c  = (idx >> 12) & 31;
    int n  = idx >> 17;
    const float* wp = w1 + c * KDIM;
    float acc = 0.f;
    for (int ci = 0; ci < CN; ci++) {
        const float* xp = x + (((size_t)n * CN + ci) << 12);
        #pragma unroll
        for (int kh = 0; kh < 3; kh++) {
            int y = hh + kh - 1;
            if ((unsigned)y >= 64u) continue;
            #pragma unroll
            for (int kw = 0; kw < 3; kw++) {
                int xw = w + kw - 1;
                if ((unsigned)xw >= 64u) continue;
                acc = fmaf(xp[(y << 6) + xw], wp[ci * 9 + kh * 3 + kw], acc);
            }
        }
    }
    hout[idx] = fmaxf(acc, 0.f);
}

// -------- w2 fp32 -> bf16 k-PERMUTED [9216][288]; also zeroes out --------
// out is 262144 floats = 65536 float4 (N*C*H*W = 2*32*64*64). BOUND = 65536.
__global__ __launch_bounds__(256) void w2_to_bf16_perm(
    const float* __restrict__ in, ushort_t* __restrict__ out_bf,
    float4* __restrict__ out_zero)
{
    int idx = blockIdx.x * 256 + threadIdx.x;   // chunk id, 9216*36 total
    if (idx < 65536)
        out_zero[idx] = make_float4(0.f, 0.f, 0.f, 0.f);
    int row = idx / 36;                          // 36 chunks per 288-k row
    int cw  = idx - row * 36;
    int g = cw >> 2, s = cw & 3;
    const float* base = in + (size_t)row * KDIM + g * 32;
    float4 lo = *(const float4*)(base + s * 4);
    float4 hi = *(const float4*)(base + 16 + s * 4);
    alignas(16) ushort_t o[8] = {f2bf(lo.x), f2bf(lo.y), f2bf(lo.z), f2bf(lo.w),
                                 f2bf(hi.x), f2bf(hi.y), f2bf(hi.z), f2bf(hi.w)};
    *(uint4*)(out_bf + (size_t)idx * 8) = *(const uint4*)o;
}

// ---------------- im2col of h, P-MAJOR k-PERMUTED bf16: Bm[p][kperm] ----------------
__global__ __launch_bounds__(256) void im2col_bf16_perm(
    const float* __restrict__ h, ushort_t* __restrict__ Bm)
{
    int idx = blockIdx.x * 256 + threadIdx.x;   // PDIM*KDIM
    int kp = idx % KDIM;
    int p  = idx / KDIM;
    // invert permutation: logical k for permuted position kp
    int pos = kp & 31, s = pos >> 3, j = pos & 7;
    int ko = (j < 4) ? (s * 4 + j) : (16 + s * 4 + j - 4);
    int k  = (kp & ~31) + ko;
    int n  = p >> 12;
    int sp = p & 4095;
    int hh = sp >> 6;
    int w  = sp & 63;
    int ci = k / 9;
    int kk = k - ci * 9;
    int kh = kk / 3;
    int kw = kk - kh * 3;
    int y  = hh + kh - 1;
    int xw = w + kw - 1;
    float v = 0.f;
    if ((unsigned)y < 64u && (unsigned)xw < 64u)
        v = h[(((size_t)n * CN + ci) << 12) + (y << 6) + xw];
    Bm[idx] = f2bf(v);
}

// ---------------- fused: MFMA GEMM + tanh + apply (counted-vmcnt pipeline) --
// Semantics (R5-proven):
//   W(co,ci,t) = tanh(rst[(co*32+ci)*9 + (t>>12), n*4096 + (t&4095)]),
//   out[n,co,sp] = sum_{ci,kk} W(co,ci, t=sp*9+kk) * x[n,ci,nbr(sp,kk)].
// Block = (tw, cg, n) via XCD-swizzled flat blockIdx (R6-proven locality).
// K-loop (T3/T4): dbuf LDS; per step:
//   issue stage(ks+1 -> buf^1); s_waitcnt vmcnt(4) [prev tile's 4 done,
//   fresh 4 in flight]; SBAR; ds_read+MFMA(buf cur); lgkmcnt(0); SBAR.
// EVERY s_barrier is wrapped in sched_barrier(0) — s_barrier is NOT a
// compiler memory fence (R9 post-mortem: gl_lds writes hoisted above the
// closing barrier raced with other waves' ds_reads).
__global__ __launch_bounds__(256) void fused_gemm_apply(
    const ushort_t* __restrict__ A, const ushort_t* __restrict__ B,
    const float* __restrict__ x, float* __restrict__ out)
{
    __shared__ ushort_t AL[2][128 * 32];   // 2 x 8 KiB
    __shared__ ushort_t BL[2][128 * 32];   // 2 x 8 KiB
    __shared__ float vred[4][128];         // per-(g, t_local) ci-summed values

    int tid = threadIdx.x;
    // bijective XCD swizzle: 4608 = 8 XCDs x 576; consecutive sb share (cg,n)
    int bid = blockIdx.x;
    int sb  = (bid & 7) * 576 + (bid >> 3);
    int tw  = sb % 288;
    int cg  = (sb / 288) & 7;
    int n   = sb / 2304;

    int lane = tid & 63, wv = tid >> 6;
    int wm = wv >> 1, wn = wv & 1;      // 2x2 wave grid: wm->m, wn->t
    int i16 = lane & 15, kg = lane >> 4;

    int T0 = tw * 128;
    int c8 = T0 >> 12;                  // block-constant rst sub-channel
    int q0 = T0 & 4095;                 // contiguous B column window start

    // staging chunk geometry (2 chunks of A + 2 of B per thread per K-step)
    int c_0 = tid, c_1 = 256 + tid;
    int row0 = c_0 >> 2, row1 = c_1 >> 2;
    int k8_0 = (((c_0 & 3) ^ ((c_0 >> 3) & 3)) << 3);  // pre-swizzled source
    int k8_1 = (((c_1 & 3) ^ ((c_1 >> 3) & 3)) << 3);
    const ushort_t* srcA0 = A +
        (size_t)((cg * 4 + (row0 >> 5)) * KDIM + (row0 & 31) * 9 + c8) * KDIM + k8_0;
    const ushort_t* srcA1 = A +
        (size_t)((cg * 4 + (row1 >> 5)) * KDIM + (row1 & 31) * 9 + c8) * KDIM + k8_1;
    const ushort_t* srcB0 = B + (size_t)((n << 12) + q0 + row0) * KDIM + k8_0;
    const ushort_t* srcB1 = B + (size_t)((n << 12) + q0 + row1) * KDIM + k8_1;
    int dst0 = wv * 512, dst1 = 2048 + wv * 512;

    f32x4 acc[4][4] = {};

    // prologue: stage K-tile 0 into buffer 0 (completion waited in-loop)
    gl_lds16(srcA0, &AL[0][dst0]);
    gl_lds16(srcA1, &AL[0][dst1]);
    gl_lds16(srcB0, &BL[0][dst0]);
    gl_lds16(srcB1, &BL[0][dst1]);

    #pragma unroll
    for (int ks = 0; ks < 9; ks++) {
        int cur = ks & 1;
        if (ks < 8) {
            int k0 = (ks + 1) * 32;
            gl_lds16(srcA0 + k0, &AL[cur ^ 1][dst0]);
            gl_lds16(srcA1 + k0, &AL[cur ^ 1][dst1]);
            gl_lds16(srcB0 + k0, &BL[cur ^ 1][dst0]);
            gl_lds16(srcB1 + k0, &BL[cur ^ 1][dst1]);
            __builtin_amdgcn_sched_barrier(0);
            asm volatile("s_waitcnt vmcnt(4)" ::: "memory");  // tile ks done
        } else {
            __builtin_amdgcn_sched_barrier(0);
            asm volatile("s_waitcnt vmcnt(0)" ::: "memory");  // last tile done
        }
        __builtin_amdgcn_sched_barrier(0);
        __builtin_amdgcn_s_barrier();       // all waves' stages visible
        __builtin_amdgcn_sched_barrier(0);

        bf16x8 af[4], bfr[4];
        #pragma unroll
        for (int mf = 0; mf < 4; mf++) {
            int row = wm * 64 + mf * 16 + i16;
            af[mf] = *(const bf16x8*)
                &AL[cur][row * 32 + ((kg ^ ((row >> 1) & 3)) << 3)];
        }
        #pragma unroll
        for (int nf = 0; nf < 4; nf++) {
            int row = wn * 64 + nf * 16 + i16;
            bfr[nf] = *(const bf16x8*)
                &BL[cur][row * 32 + ((kg ^ ((row >> 1) & 3)) << 3)];
        }
        #pragma unroll
        for (int mf = 0; mf < 4; mf++)
            #pragma unroll
            for (int nf = 0; nf < 4; nf++)
                acc[mf][nf] = __builtin_amdgcn_mfma_f32_16x16x32_bf16(
                    af[mf], bfr[nf], acc[mf][nf], 0, 0, 0);

        // reads fully retired before the WAR window opens (cross-path LDS
        // ordering between in-flight ds_read and gl_lds write is not HW-
        // guaranteed); lgkmcnt is already ~0 here via the MFMA operand waits.
        __builtin_amdgcn_sched_barrier(0);
        asm volatile("s_waitcnt lgkmcnt(0)" ::: "memory");
        __builtin_amdgcn_sched_barrier(0);
        __builtin_amdgcn_s_barrier();       // reads done before next stage
        __builtin_amdgcn_sched_barrier(0);
    }

    // ---- epilogue: tanh, x-weighted, reduce over ci (m) then kk (t) ----
    // D layout: m_local = wm*64 + mf*16 + kg*4 + r, t_local = wn*64 + nf*16 + i16
    // ci = (mf*16 + kg*4 + r) & 31; g = 2*wm + (mf>>1)   (R5-proven)
    const float* xn = x + (((size_t)n * CN) << 12);
    #pragma unroll
    for (int nf = 0; nf < 4; nf++) {
        int t  = T0 + wn * 64 + nf * 16 + i16;
        uint sp = ((uint)t * 58255u) >> 19;       // t/9, exact for t < 74898
        int kk = t - (int)sp * 9;
        int kh = (kk * 11) >> 5;                  // kk/3
        int kw = kk - kh * 3;
        int y  = (int)(sp >> 6) + kh - 1;
        int xw = (int)(sp & 63) + kw - 1;
        bool ok = ((unsigned)y < 64u) && ((unsigned)xw < 64u);
        int poff = (y << 6) + xw;
        float xa[4], xb[4];
        #pragma unroll
        for (int r = 0; r < 4; r++) {
            int cia = kg * 4 + r;
            xa[r] = ok ? xn[((size_t)cia << 12) + poff] : 0.f;
            xb[r] = ok ? xn[((size_t)(cia + 16) << 12) + poff] : 0.f;
        }
        float s0 = 0.f, s1 = 0.f;
        #pragma unroll
        for (int r = 0; r < 4; r++) {
            s0 = fmaf(fast_tanh(acc[0][nf][r]), xa[r], s0);
            s0 = fmaf(fast_tanh(acc[1][nf][r]), xb[r], s0);
            s1 = fmaf(fast_tanh(acc[2][nf][r]), xa[r], s1);
            s1 = fmaf(fast_tanh(acc[3][nf][r]), xb[r], s1);
        }
        // sum the 4 kg groups (lanes l, l^16, l^32, l^48 share t) -> all 32 ci
        s0 += __shfl_xor(s0, 16); s0 += __shfl_xor(s0, 32);
        s1 += __shfl_xor(s1, 16); s1 += __shfl_xor(s1, 32);
        if (kg == 0) {
            vred[2 * wm + 0][wn * 64 + nf * 16 + i16] = s0;
            vred[2 * wm + 1][wn * 64 + nf * 16 + i16] = s1;
        }
    }
    __syncthreads();

    // ---- fold 9 t's per pixel, atomicAdd (2-way only on window boundaries) ----
    if (tid < 64) {
        int g  = tid >> 4, bi = tid & 15;
        uint spA = ((uint)T0 * 58255u) >> 19;
        int sp = (int)spA + bi;
        int lo = sp * 9;     if (lo < T0) lo = T0;
        int hi = sp * 9 + 9; if (hi > T0 + 128) hi = T0 + 128;
        if (lo < hi) {
            float s = 0.f;
            for (int t = lo; t < hi; t++) s += vred[g][t - T0];
            atomicAdd(&out[(((size_t)n * CN + cg * 4 + g) << 12) + sp], s);
        }
    }
}

extern "C" void kernel_launch(void* const* d_in, const int* in_sizes, int n_in,
                              void* d_out, int out_size, void* d_ws, size_t ws_size,
                              hipStream_t stream) {
    const float* x  = (const float*)d_in[0];
    const float* w1 = (const float*)d_in[1];
    const float* w2 = (const float*)d_in[2];
    float* out = (float*)d_out;
    char* ws = (char*)d_ws;

    float*    hbuf  = (float*)ws;                       // 1 MiB
    ushort_t* Bm_bf = (ushort_t*)(ws + 1048576u);       // 8192*288*2 = 4718592 B
    ushort_t* A_bf  = (ushort_t*)(ws + 5767168u);       // 9216*288*2 = 5308416 B

    hipLaunchKernelGGL(conv1_relu, dim3(1024), dim3(256), 0, stream, x, w1, hbuf);
    hipLaunchKernelGGL(w2_to_bf16_perm, dim3(1296), dim3(256), 0, stream,
                       w2, A_bf, (float4*)out);
    hipLaunchKernelGGL(im2col_bf16_perm, dim3((PDIM * KDIM) / 256), dim3(256), 0,
                       stream, hbuf, Bm_bf);
    hipLaunchKernelGGL(fused_gemm_apply, dim3(4608), dim3(256), 0, stream,
                       A_bf, Bm_bf, x, out);
}

// Round 11
// 118.382 us; speedup vs baseline: 1.5493x; 1.2386x over previous
//
#include <hip/hip_runtime.h>

typedef unsigned int uint;
typedef unsigned short ushort_t;

// Problem constants
#define CN 32          // channels
#define HW 4096        // H*W
#define KDIM 288       // C*9
#define PDIM 8192      // N*HW
#define NB 2           // batch

typedef __attribute__((ext_vector_type(8))) short bf16x8;
typedef __attribute__((ext_vector_type(4))) float f32x4;

static __device__ __forceinline__ ushort_t f2bf(float f) {
    uint u = __float_as_uint(f);
    uint r = (u + 0x7fffu + ((u >> 16) & 1u)) >> 16;
    return (ushort_t)r;
}

static __device__ __forceinline__ void gl_lds16(const void* g, void* l) {
    __builtin_amdgcn_global_load_lds(
        (const __attribute__((address_space(1))) unsigned int*)g,
        (__attribute__((address_space(3))) unsigned int*)l, 16, 0, 0);
}

static __device__ __forceinline__ float fast_tanh(float v) {
    // tanh(v) = 1 - 2/(1+e^{2v}); v_rcp_f32 instead of IEEE divide
    // (R10 post-mortem: 64 full divides/thread = ~640 VALU insts, the
    //  dominant VALU load). rcp(inf)=0 -> +-1 exact; err ~1e-6.
    float e = __expf(2.0f * v);
    return 1.0f - 2.0f * __builtin_amdgcn_rcpf(e + 1.0f);
}

// k-permutation within each 32-k group: 16B chunk slot s holds logical
// k = {g*32 + 4s..4s+3, g*32 + 16+4s..16+4s+3}. Lane kg's whole MFMA
// fragment (k = kg*4+j, 16+kg*4+j) is then ONE contiguous 16B LDS chunk.

// ---------------- conv1 + relu: x (N,32,64,64) -> h ----------------
// 4 outputs/thread along w, float4 row loads, w1 row staged in LDS.
// 65536 threads = 256 blocks; block = single (n,c): c=(bid>>2)&31, n=bid>>7.
__global__ __launch_bounds__(256) void conv1_relu(
    const float* __restrict__ x, const float* __restrict__ w1,
    float* __restrict__ hout)
{
    __shared__ float w1s[KDIM];
    int bid = blockIdx.x;
    int c = (bid >> 2) & 31;
    int n = bid >> 7;
    for (int j = threadIdx.x; j < KDIM; j += 256) w1s[j] = w1[c * KDIM + j];
    __syncthreads();

    int idx = bid * 256 + threadIdx.x;
    int ws0 = (idx & 15) * 4;          // w strip start
    int hh  = (idx >> 4) & 63;

    float acc0 = 0.f, acc1 = 0.f, acc2 = 0.f, acc3 = 0.f;
    for (int ci = 0; ci < CN; ci++) {
        const float* xp = x + (((size_t)(n * CN + ci)) << 12);
        #pragma unroll
        for (int kh = 0; kh < 3; kh++) {
            int y = hh + kh - 1;
            if ((unsigned)y >= 64u) continue;
            const float* row = xp + (y << 6);
            float4 v = *(const float4*)(row + ws0);
            float left  = (ws0 > 0)  ? row[ws0 - 1] : 0.f;
            float right = (ws0 < 60) ? row[ws0 + 4] : 0.f;
            float rb[6] = {left, v.x, v.y, v.z, v.w, right};
            const float* wp = &w1s[ci * 9 + kh * 3];
            #pragma unroll
            for (int kw = 0; kw < 3; kw++) {
                float wgt = wp[kw];
                acc0 = fmaf(wgt, rb[0 + kw], acc0);
                acc1 = fmaf(wgt, rb[1 + kw], acc1);
                acc2 = fmaf(wgt, rb[2 + kw], acc2);
                acc3 = fmaf(wgt, rb[3 + kw], acc3);
            }
        }
    }
    float4 o = make_float4(fmaxf(acc0, 0.f), fmaxf(acc1, 0.f),
                           fmaxf(acc2, 0.f), fmaxf(acc3, 0.f));
    *(float4*)(hout + (((size_t)(n * CN + c)) << 12) + (hh << 6) + ws0) = o;
}

// -------- w2 fp32 -> bf16 k-PERMUTED [9216][288]; also zeroes out --------
// out is 262144 floats = 65536 float4 (N*C*H*W = 2*32*64*64). BOUND = 65536.
__global__ __launch_bounds__(256) void w2_to_bf16_perm(
    const float* __restrict__ in, ushort_t* __restrict__ out_bf,
    float4* __restrict__ out_zero)
{
    int idx = blockIdx.x * 256 + threadIdx.x;   // chunk id, 9216*36 total
    if (idx < 65536)
        out_zero[idx] = make_float4(0.f, 0.f, 0.f, 0.f);
    int row = idx / 36;                          // 36 chunks per 288-k row
    int cw  = idx - row * 36;
    int g = cw >> 2, s = cw & 3;
    const float* base = in + (size_t)row * KDIM + g * 32;
    float4 lo = *(const float4*)(base + s * 4);
    float4 hi = *(const float4*)(base + 16 + s * 4);
    alignas(16) ushort_t o[8] = {f2bf(lo.x), f2bf(lo.y), f2bf(lo.z), f2bf(lo.w),
                                 f2bf(hi.x), f2bf(hi.y), f2bf(hi.z), f2bf(hi.w)};
    *(uint4*)(out_bf + (size_t)idx * 8) = *(const uint4*)o;
}

// ------ im2col of h, P-MAJOR k-PERMUTED bf16: one 16B chunk per thread ------
// chunk id = p*36 + cw; produces permuted positions cw*8..cw*8+7 of row p.
__global__ __launch_bounds__(256) void im2col_bf16_perm(
    const float* __restrict__ h, ushort_t* __restrict__ Bm)
{
    int idx = blockIdx.x * 256 + threadIdx.x;   // PDIM*36 = 294912 chunks
    int p  = idx / 36;
    int cw = idx - p * 36;
    int g = cw >> 2, s = cw & 3;
    int n  = p >> 12;
    int sp = p & 4095;
    int hh = sp >> 6;
    int w  = sp & 63;
    const float* hn = h + (((size_t)n * CN) << 12);
    alignas(16) ushort_t o[8];
    #pragma unroll
    for (int j = 0; j < 8; j++) {
        int ko = (j < 4) ? (s * 4 + j) : (12 + s * 4 + j);  // 16+s*4+(j-4)
        int k  = g * 32 + ko;
        int ci = (k * 57) >> 9;            // k/9, exact for k < 4500
        int kk = k - ci * 9;
        int kh = (kk * 11) >> 5;           // kk/3
        int kw = kk - kh * 3;
        int y  = hh + kh - 1;
        int xw = w + kw - 1;
        float v = 0.f;
        if ((unsigned)y < 64u && (unsigned)xw < 64u)
            v = hn[((size_t)ci << 12) + (y << 6) + xw];
        o[j] = f2bf(v);
    }
    *(uint4*)(Bm + (size_t)idx * 8) = *(const uint4*)o;
}

// ---------------- fused: MFMA GEMM + tanh + apply (counted-vmcnt pipeline) --
// Semantics (R5-proven):
//   W(co,ci,t) = tanh(rst[(co*32+ci)*9 + (t>>12), n*4096 + (t&4095)]),
//   out[n,co,sp] = sum_{ci,kk} W(co,ci, t=sp*9+kk) * x[n,ci,nbr(sp,kk)].
// Block = (tw, cg, n) via XCD-swizzled flat blockIdx (R6-proven locality).
// K-loop (R10-proven): dbuf LDS; per step {issue stage(ks+1 -> buf^1);
// vmcnt(4); SBAR; ds_read+MFMA(buf cur); lgkmcnt(0); SBAR}; every barrier
// wrapped in sched_barrier(0) (s_barrier is not a compiler fence).
__global__ __launch_bounds__(256, 4) void fused_gemm_apply(
    const ushort_t* __restrict__ A, const ushort_t* __restrict__ B,
    const float* __restrict__ x, float* __restrict__ out)
{
    __shared__ ushort_t AL[2][128 * 32];   // 2 x 8 KiB
    __shared__ ushort_t BL[2][128 * 32];   // 2 x 8 KiB
    __shared__ float vred[4][128];         // per-(g, t_local) ci-summed values

    int tid = threadIdx.x;
    // bijective XCD swizzle: 4608 = 8 XCDs x 576; consecutive sb share (cg,n)
    int bid = blockIdx.x;
    int sb  = (bid & 7) * 576 + (bid >> 3);
    int tw  = sb % 288;
    int cg  = (sb / 288) & 7;
    int n   = sb / 2304;

    int lane = tid & 63, wv = tid >> 6;
    int wm = wv >> 1, wn = wv & 1;      // 2x2 wave grid: wm->m, wn->t
    int i16 = lane & 15, kg = lane >> 4;

    int T0 = tw * 128;
    int c8 = T0 >> 12;                  // block-constant rst sub-channel
    int q0 = T0 & 4095;                 // contiguous B column window start

    // staging chunk geometry (2 chunks of A + 2 of B per thread per K-step)
    int c_0 = tid, c_1 = 256 + tid;
    int row0 = c_0 >> 2, row1 = c_1 >> 2;
    int k8_0 = (((c_0 & 3) ^ ((c_0 >> 3) & 3)) << 3);  // pre-swizzled source
    int k8_1 = (((c_1 & 3) ^ ((c_1 >> 3) & 3)) << 3);
    const ushort_t* srcA0 = A +
        (size_t)((cg * 4 + (row0 >> 5)) * KDIM + (row0 & 31) * 9 + c8) * KDIM + k8_0;
    const ushort_t* srcA1 = A +
        (size_t)((cg * 4 + (row1 >> 5)) * KDIM + (row1 & 31) * 9 + c8) * KDIM + k8_1;
    const ushort_t* srcB0 = B + (size_t)((n << 12) + q0 + row0) * KDIM + k8_0;
    const ushort_t* srcB1 = B + (size_t)((n << 12) + q0 + row1) * KDIM + k8_1;
    int dst0 = wv * 512, dst1 = 2048 + wv * 512;

    f32x4 acc[4][4] = {};

    // prologue: stage K-tile 0 into buffer 0 (completion waited in-loop)
    gl_lds16(srcA0, &AL[0][dst0]);
    gl_lds16(srcA1, &AL[0][dst1]);
    gl_lds16(srcB0, &BL[0][dst0]);
    gl_lds16(srcB1, &BL[0][dst1]);

    #pragma unroll
    for (int ks = 0; ks < 9; ks++) {
        int cur = ks & 1;
        if (ks < 8) {
            int k0 = (ks + 1) * 32;
            gl_lds16(srcA0 + k0, &AL[cur ^ 1][dst0]);
            gl_lds16(srcA1 + k0, &AL[cur ^ 1][dst1]);
            gl_lds16(srcB0 + k0, &BL[cur ^ 1][dst0]);
            gl_lds16(srcB1 + k0, &BL[cur ^ 1][dst1]);
            __builtin_amdgcn_sched_barrier(0);
            asm volatile("s_waitcnt vmcnt(4)" ::: "memory");  // tile ks done
        } else {
            __builtin_amdgcn_sched_barrier(0);
            asm volatile("s_waitcnt vmcnt(0)" ::: "memory");  // last tile done
        }
        __builtin_amdgcn_sched_barrier(0);
        __builtin_amdgcn_s_barrier();       // all waves' stages visible
        __builtin_amdgcn_sched_barrier(0);

        bf16x8 af[4], bfr[4];
        #pragma unroll
        for (int mf = 0; mf < 4; mf++) {
            int row = wm * 64 + mf * 16 + i16;
            af[mf] = *(const bf16x8*)
                &AL[cur][row * 32 + ((kg ^ ((row >> 1) & 3)) << 3)];
        }
        #pragma unroll
        for (int nf = 0; nf < 4; nf++) {
            int row = wn * 64 + nf * 16 + i16;
            bfr[nf] = *(const bf16x8*)
                &BL[cur][row * 32 + ((kg ^ ((row >> 1) & 3)) << 3)];
        }
        #pragma unroll
        for (int mf = 0; mf < 4; mf++)
            #pragma unroll
            for (int nf = 0; nf < 4; nf++)
                acc[mf][nf] = __builtin_amdgcn_mfma_f32_16x16x32_bf16(
                    af[mf], bfr[nf], acc[mf][nf], 0, 0, 0);

        // reads fully retired before the WAR window opens
        __builtin_amdgcn_sched_barrier(0);
        asm volatile("s_waitcnt lgkmcnt(0)" ::: "memory");
        __builtin_amdgcn_sched_barrier(0);
        __builtin_amdgcn_s_barrier();       // reads done before next stage
        __builtin_amdgcn_sched_barrier(0);
    }

    // ---- epilogue: tanh, x-weighted, reduce over ci (m) then kk (t) ----
    // D layout: m_local = wm*64 + mf*16 + kg*4 + r, t_local = wn*64 + nf*16 + i16
    // ci = (mf*16 + kg*4 + r) & 31; g = 2*wm + (mf>>1)   (R5-proven)
    const float* xn = x + (((size_t)n * CN) << 12);
    #pragma unroll
    for (int nf = 0; nf < 4; nf++) {
        int t  = T0 + wn * 64 + nf * 16 + i16;
        uint sp = ((uint)t * 58255u) >> 19;       // t/9, exact for t < 74898
        int kk = t - (int)sp * 9;
        int kh = (kk * 11) >> 5;                  // kk/3
        int kw = kk - kh * 3;
        int y  = (int)(sp >> 6) + kh - 1;
        int xw = (int)(sp & 63) + kw - 1;
        bool ok = ((unsigned)y < 64u) && ((unsigned)xw < 64u);
        int poff = (y << 6) + xw;
        float xa[4], xb[4];
        #pragma unroll
        for (int r = 0; r < 4; r++) {
            int cia = kg * 4 + r;
            xa[r] = ok ? xn[((size_t)cia << 12) + poff] : 0.f;
            xb[r] = ok ? xn[((size_t)(cia + 16) << 12) + poff] : 0.f;
        }
        float s0 = 0.f, s1 = 0.f;
        #pragma unroll
        for (int r = 0; r < 4; r++) {
            s0 = fmaf(fast_tanh(acc[0][nf][r]), xa[r], s0);
            s0 = fmaf(fast_tanh(acc[1][nf][r]), xb[r], s0);
            s1 = fmaf(fast_tanh(acc[2][nf][r]), xa[r], s1);
            s1 = fmaf(fast_tanh(acc[3][nf][r]), xb[r], s1);
        }
        // sum the 4 kg groups (lanes l, l^16, l^32, l^48 share t) -> all 32 ci
        s0 += __shfl_xor(s0, 16); s0 += __shfl_xor(s0, 32);
        s1 += __shfl_xor(s1, 16); s1 += __shfl_xor(s1, 32);
        if (kg == 0) {
            vred[2 * wm + 0][wn * 64 + nf * 16 + i16] = s0;
            vred[2 * wm + 1][wn * 64 + nf * 16 + i16] = s1;
        }
    }
    __syncthreads();

    // ---- fold 9 t's per pixel, atomicAdd (2-way only on window boundaries) ----
    if (tid < 64) {
        int g  = tid >> 4, bi = tid & 15;
        uint spA = ((uint)T0 * 58255u) >> 19;
        int sp = (int)spA + bi;
        int lo = sp * 9;     if (lo < T0) lo = T0;
        int hi = sp * 9 + 9; if (hi > T0 + 128) hi = T0 + 128;
        if (lo < hi) {
            float s = 0.f;
            for (int t = lo; t < hi; t++) s += vred[g][t - T0];
            atomicAdd(&out[(((size_t)n * CN + cg * 4 + g) << 12) + sp], s);
        }
    }
}

extern "C" void kernel_launch(void* const* d_in, const int* in_sizes, int n_in,
                              void* d_out, int out_size, void* d_ws, size_t ws_size,
                              hipStream_t stream) {
    const float* x  = (const float*)d_in[0];
    const float* w1 = (const float*)d_in[1];
    const float* w2 = (const float*)d_in[2];
    float* out = (float*)d_out;
    char* ws = (char*)d_ws;

    float*    hbuf  = (float*)ws;                       // 1 MiB
    ushort_t* Bm_bf = (ushort_t*)(ws + 1048576u);       // 8192*288*2 = 4718592 B
    ushort_t* A_bf  = (ushort_t*)(ws + 5767168u);       // 9216*288*2 = 5308416 B

    hipLaunchKernelGGL(conv1_relu, dim3(256), dim3(256), 0, stream, x, w1, hbuf);
    hipLaunchKernelGGL(w2_to_bf16_perm, dim3(1296), dim3(256), 0, stream,
                       w2, A_bf, (float4*)out);
    hipLaunchKernelGGL(im2col_bf16_perm, dim3(1152), dim3(256), 0,
                       stream, hbuf, Bm_bf);
    hipLaunchKernelGGL(fused_gemm_apply, dim3(4608), dim3(256), 0, stream,
                       A_bf, Bm_bf, x, out);
}

// Round 12
// 114.499 us; speedup vs baseline: 1.6019x; 1.0339x over previous
//
#include <hip/hip_runtime.h>

typedef unsigned int uint;
typedef unsigned short ushort_t;

// Problem constants
#define CN 32          // channels
#define HW 4096        // H*W
#define KDIM 288       // C*9
#define PDIM 8192      // N*HW
#define NB 2           // batch

typedef __attribute__((ext_vector_type(8))) short bf16x8;
typedef __attribute__((ext_vector_type(4))) float f32x4;

static __device__ __forceinline__ ushort_t f2bf(float f) {
    uint u = __float_as_uint(f);
    uint r = (u + 0x7fffu + ((u >> 16) & 1u)) >> 16;
    return (ushort_t)r;
}

static __device__ __forceinline__ void gl_lds16(const void* g, void* l) {
    __builtin_amdgcn_global_load_lds(
        (const __attribute__((address_space(1))) unsigned int*)g,
        (__attribute__((address_space(3))) unsigned int*)l, 16, 0, 0);
}

static __device__ __forceinline__ float fast_tanh(float v) {
    // tanh(v) = 1 - 2*rcp(1+e^{2v}); rcp(inf)=0 -> +-1 exact; err ~1e-6
    float e = __expf(2.0f * v);
    return 1.0f - 2.0f * __builtin_amdgcn_rcpf(e + 1.0f);
}

// k-permutation within each 32-k group: 16B chunk slot s holds logical
// k = {g*32 + 4s..4s+3, g*32 + 16+4s..16+4s+3}. Lane kg's whole MFMA
// fragment (k = kg*4+j, 16+kg*4+j) is then ONE contiguous 16B LDS chunk.

// ------------- prep: conv1+relu (blocks 0..255) | w2->bf16 perm + zero-out --
// (merged: independent work, saves one launch)
__global__ __launch_bounds__(256) void prep_kernel(
    const float* __restrict__ x, const float* __restrict__ w1,
    const float* __restrict__ w2, float* __restrict__ hout,
    ushort_t* __restrict__ A_bf, float4* __restrict__ out_zero)
{
    __shared__ float w1s[KDIM];
    int bb = blockIdx.x;
    if (bb < 256) {
        // conv1+relu: 4 outputs/thread along w, float4 row loads, w1 in LDS
        int c = (bb >> 2) & 31;
        int n = bb >> 7;
        for (int j = threadIdx.x; j < KDIM; j += 256) w1s[j] = w1[c * KDIM + j];
        __syncthreads();

        int idx = bb * 256 + threadIdx.x;
        int ws0 = (idx & 15) * 4;
        int hh  = (idx >> 4) & 63;

        float acc0 = 0.f, acc1 = 0.f, acc2 = 0.f, acc3 = 0.f;
        for (int ci = 0; ci < CN; ci++) {
            const float* xp = x + (((size_t)(n * CN + ci)) << 12);
            #pragma unroll
            for (int kh = 0; kh < 3; kh++) {
                int y = hh + kh - 1;
                if ((unsigned)y >= 64u) continue;
                const float* row = xp + (y << 6);
                float4 v = *(const float4*)(row + ws0);
                float left  = (ws0 > 0)  ? row[ws0 - 1] : 0.f;
                float right = (ws0 < 60) ? row[ws0 + 4] : 0.f;
                float rb[6] = {left, v.x, v.y, v.z, v.w, right};
                const float* wp = &w1s[ci * 9 + kh * 3];
                #pragma unroll
                for (int kw = 0; kw < 3; kw++) {
                    float wgt = wp[kw];
                    acc0 = fmaf(wgt, rb[0 + kw], acc0);
                    acc1 = fmaf(wgt, rb[1 + kw], acc1);
                    acc2 = fmaf(wgt, rb[2 + kw], acc2);
                    acc3 = fmaf(wgt, rb[3 + kw], acc3);
                }
            }
        }
        float4 o = make_float4(fmaxf(acc0, 0.f), fmaxf(acc1, 0.f),
                               fmaxf(acc2, 0.f), fmaxf(acc3, 0.f));
        *(float4*)(hout + (((size_t)(n * CN + c)) << 12) + (hh << 6) + ws0) = o;
    } else {
        // w2 fp32 -> bf16 k-permuted [9216][288]; also zero out (65536 float4)
        int idx = (bb - 256) * 256 + threadIdx.x;   // 0..331775
        if (idx < 65536)
            out_zero[idx] = make_float4(0.f, 0.f, 0.f, 0.f);
        int row = idx / 36;
        int cw  = idx - row * 36;
        int g = cw >> 2, s = cw & 3;
        const float* base = w2 + (size_t)row * KDIM + g * 32;
        float4 lo = *(const float4*)(base + s * 4);
        float4 hi = *(const float4*)(base + 16 + s * 4);
        alignas(16) ushort_t o[8] = {f2bf(lo.x), f2bf(lo.y), f2bf(lo.z), f2bf(lo.w),
                                     f2bf(hi.x), f2bf(hi.y), f2bf(hi.z), f2bf(hi.w)};
        *(uint4*)(A_bf + (size_t)idx * 8) = *(const uint4*)o;
    }
}

// ------ im2col of h, P-MAJOR k-PERMUTED bf16: one 16B chunk per thread ------
__global__ __launch_bounds__(256) void im2col_bf16_perm(
    const float* __restrict__ h, ushort_t* __restrict__ Bm)
{
    int idx = blockIdx.x * 256 + threadIdx.x;   // PDIM*36 = 294912 chunks
    int p  = idx / 36;
    int cw = idx - p * 36;
    int g = cw >> 2, s = cw & 3;
    int n  = p >> 12;
    int sp = p & 4095;
    int hh = sp >> 6;
    int w  = sp & 63;
    const float* hn = h + (((size_t)n * CN) << 12);
    alignas(16) ushort_t o[8];
    #pragma unroll
    for (int j = 0; j < 8; j++) {
        int ko = (j < 4) ? (s * 4 + j) : (12 + s * 4 + j);  // 16+s*4+(j-4)
        int k  = g * 32 + ko;
        int ci = (k * 57) >> 9;            // k/9, exact for k < 4500
        int kk = k - ci * 9;
        int kh = (kk * 11) >> 5;           // kk/3
        int kw = kk - kh * 3;
        int y  = hh + kh - 1;
        int xw = w + kw - 1;
        float v = 0.f;
        if ((unsigned)y < 64u && (unsigned)xw < 64u)
            v = hn[((size_t)ci << 12) + (y << 6) + xw];
        o[j] = f2bf(v);
    }
    *(uint4*)(Bm + (size_t)idx * 8) = *(const uint4*)o;
}

// ------- fused: MFMA GEMM + tanh + apply (8-wave 128x256 tile, dbuf) --------
// Semantics (R5-proven):
//   W(co,ci,t) = tanh(rst[(co*32+ci)*9 + (t>>12), n*4096 + (t&4095)]),
//   out[n,co,sp] = sum_{ci,kk} W(co,ci, t=sp*9+kk) * x[n,ci,nbr(sp,kk)].
// Block = (tw, cg, n), t-window [T0, T0+256), T0 = tw*256 (256 | 4096 so c8
// block-constant). 512 threads = 8 waves, grid 2m x 4t; per-wave frag
// geometry (4x4 of 16x16, acc, epilogue) IDENTICAL to the R10-proven kernel.
// K-loop (R10-proven sync): dbuf LDS; per step {issue 3 gl_lds (1A+2B);
// vmcnt(3); SBAR; ds_read+MFMA; lgkmcnt(0); SBAR}; sched_barrier(0) wraps.
__global__ __launch_bounds__(512, 4) void fused_gemm_apply(
    const ushort_t* __restrict__ A, const ushort_t* __restrict__ B,
    const float* __restrict__ x, float* __restrict__ out)
{
    __shared__ ushort_t AL[2][128 * 32];   // 2 x 8 KiB
    __shared__ ushort_t BL[2][256 * 32];   // 2 x 16 KiB
    __shared__ float vred[4][256];         // per-(g, t_local) ci-summed values

    int tid = threadIdx.x;
    // bijective XCD swizzle: 2304 = 8 XCDs x 288
    int bid = blockIdx.x;
    int sb  = (bid & 7) * 288 + (bid >> 3);
    int tw  = sb % 144;                 // 144 t-windows of 256
    int cg  = (sb / 144) & 7;
    int n   = sb / 1152;

    int lane = tid & 63, wv = tid >> 6;
    int wm = wv >> 2, wt = wv & 3;      // 2m x 4t wave grid
    int i16 = lane & 15, kg = lane >> 4;

    int T0 = tw * 256;
    int c8 = T0 >> 12;                  // block-constant rst sub-channel
    int q0 = T0 & 4095;                 // contiguous B column window start

    // staging: per K-step, thread stages 1 A chunk + 2 B chunks (16B each)
    int cA = tid;                        // 0..511 = 128 rows x 4 slots
    int rA = cA >> 2;
    int k8A = (((cA & 3) ^ ((cA >> 3) & 3)) << 3);   // pre-swizzled source
    const ushort_t* srcA = A +
        (size_t)((cg * 4 + (rA >> 5)) * KDIM + (rA & 31) * 9 + c8) * KDIM + k8A;
    int cB0 = tid, cB1 = 512 + tid;      // 1024 chunks = 256 rows x 4 slots
    int rB0 = cB0 >> 2, rB1 = cB1 >> 2;
    int k8B0 = (((cB0 & 3) ^ ((cB0 >> 3) & 3)) << 3);
    int k8B1 = (((cB1 & 3) ^ ((cB1 >> 3) & 3)) << 3);
    const ushort_t* srcB0 = B + (size_t)((n << 12) + q0 + rB0) * KDIM + k8B0;
    const ushort_t* srcB1 = B + (size_t)((n << 12) + q0 + rB1) * KDIM + k8B1;
    int dstA = wv * 512;                 // wave-uniform bases (lane*16B added by HW)
    int dstB0 = wv * 512, dstB1 = 4096 + wv * 512;

    f32x4 acc[4][4] = {};

    // prologue: stage K-tile 0 into buffer 0 (completion waited in-loop)
    gl_lds16(srcA,  &AL[0][dstA]);
    gl_lds16(srcB0, &BL[0][dstB0]);
    gl_lds16(srcB1, &BL[0][dstB1]);

    #pragma unroll
    for (int ks = 0; ks < 9; ks++) {
        int cur = ks & 1;
        if (ks < 8) {
            int k0 = (ks + 1) * 32;
            gl_lds16(srcA + k0,  &AL[cur ^ 1][dstA]);
            gl_lds16(srcB0 + k0, &BL[cur ^ 1][dstB0]);
            gl_lds16(srcB1 + k0, &BL[cur ^ 1][dstB1]);
            __builtin_amdgcn_sched_barrier(0);
            asm volatile("s_waitcnt vmcnt(3)" ::: "memory");  // tile ks done
        } else {
            __builtin_amdgcn_sched_barrier(0);
            asm volatile("s_waitcnt vmcnt(0)" ::: "memory");  // last tile done
        }
        __builtin_amdgcn_sched_barrier(0);
        __builtin_amdgcn_s_barrier();       // all waves' stages visible
        __builtin_amdgcn_sched_barrier(0);

        bf16x8 af[4], bfr[4];
        #pragma unroll
        for (int mf = 0; mf < 4; mf++) {
            int row = wm * 64 + mf * 16 + i16;
            af[mf] = *(const bf16x8*)
                &AL[cur][row * 32 + ((kg ^ ((row >> 1) & 3)) << 3)];
        }
        #pragma unroll
        for (int nf = 0; nf < 4; nf++) {
            int row = wt * 64 + nf * 16 + i16;
            bfr[nf] = *(const bf16x8*)
                &BL[cur][row * 32 + ((kg ^ ((row >> 1) & 3)) << 3)];
        }
        #pragma unroll
        for (int mf = 0; mf < 4; mf++)
            #pragma unroll
            for (int nf = 0; nf < 4; nf++)
                acc[mf][nf] = __builtin_amdgcn_mfma_f32_16x16x32_bf16(
                    af[mf], bfr[nf], acc[mf][nf], 0, 0, 0);

        // reads fully retired before the WAR window opens
        __builtin_amdgcn_sched_barrier(0);
        asm volatile("s_waitcnt lgkmcnt(0)" ::: "memory");
        __builtin_amdgcn_sched_barrier(0);
        __builtin_amdgcn_s_barrier();       // reads done before next stage
        __builtin_amdgcn_sched_barrier(0);
    }

    // ---- epilogue: tanh, x-weighted, reduce over ci (m) then kk (t) ----
    // D layout: m_local = wm*64 + mf*16 + kg*4 + r, t_local = wt*64 + nf*16 + i16
    // ci = (mf*16 + kg*4 + r) & 31; g = 2*wm + (mf>>1)   (R5-proven)
    const float* xn = x + (((size_t)n * CN) << 12);
    #pragma unroll
    for (int nf = 0; nf < 4; nf++) {
        int t  = T0 + wt * 64 + nf * 16 + i16;
        uint sp = ((uint)t * 58255u) >> 19;       // t/9, exact for t < 74898
        int kk = t - (int)sp * 9;
        int kh = (kk * 11) >> 5;                  // kk/3
        int kw = kk - kh * 3;
        int y  = (int)(sp >> 6) + kh - 1;
        int xw = (int)(sp & 63) + kw - 1;
        bool ok = ((unsigned)y < 64u) && ((unsigned)xw < 64u);
        int poff = (y << 6) + xw;
        float xa[4], xb[4];
        #pragma unroll
        for (int r = 0; r < 4; r++) {
            int cia = kg * 4 + r;
            xa[r] = ok ? xn[((size_t)cia << 12) + poff] : 0.f;
            xb[r] = ok ? xn[((size_t)(cia + 16) << 12) + poff] : 0.f;
        }
        float s0 = 0.f, s1 = 0.f;
        #pragma unroll
        for (int r = 0; r < 4; r++) {
            s0 = fmaf(fast_tanh(acc[0][nf][r]), xa[r], s0);
            s0 = fmaf(fast_tanh(acc[1][nf][r]), xb[r], s0);
            s1 = fmaf(fast_tanh(acc[2][nf][r]), xa[r], s1);
            s1 = fmaf(fast_tanh(acc[3][nf][r]), xb[r], s1);
        }
        // sum the 4 kg groups (lanes l, l^16, l^32, l^48 share t) -> all 32 ci
        s0 += __shfl_xor(s0, 16); s0 += __shfl_xor(s0, 32);
        s1 += __shfl_xor(s1, 16); s1 += __shfl_xor(s1, 32);
        if (kg == 0) {
            vred[2 * wm + 0][wt * 64 + nf * 16 + i16] = s0;
            vred[2 * wm + 1][wt * 64 + nf * 16 + i16] = s1;
        }
    }
    __syncthreads();

    // ---- fold 9 t's per pixel, atomicAdd (2-way only on window boundaries) ----
    if (tid < 128) {
        int g  = tid >> 5, bi = tid & 31;        // up to 30 pixels per window
        uint spA = ((uint)T0 * 58255u) >> 19;
        int sp = (int)spA + bi;
        int lo = sp * 9;     if (lo < T0) lo = T0;
        int hi = sp * 9 + 9; if (hi > T0 + 256) hi = T0 + 256;
        if (lo < hi) {
            float s = 0.f;
            for (int t = lo; t < hi; t++) s += vred[g][t - T0];
            atomicAdd(&out[(((size_t)n * CN + cg * 4 + g) << 12) + sp], s);
        }
    }
}

extern "C" void kernel_launch(void* const* d_in, const int* in_sizes, int n_in,
                              void* d_out, int out_size, void* d_ws, size_t ws_size,
                              hipStream_t stream) {
    const float* x  = (const float*)d_in[0];
    const float* w1 = (const float*)d_in[1];
    const float* w2 = (const float*)d_in[2];
    float* out = (float*)d_out;
    char* ws = (char*)d_ws;

    float*    hbuf  = (float*)ws;                       // 1 MiB
    ushort_t* Bm_bf = (ushort_t*)(ws + 1048576u);       // 8192*288*2 = 4718592 B
    ushort_t* A_bf  = (ushort_t*)(ws + 5767168u);       // 9216*288*2 = 5308416 B

    hipLaunchKernelGGL(prep_kernel, dim3(1552), dim3(256), 0, stream,
                       x, w1, w2, hbuf, A_bf, (float4*)out);
    hipLaunchKernelGGL(im2col_bf16_perm, dim3(1152), dim3(256), 0,
                       stream, hbuf, Bm_bf);
    hipLaunchKernelGGL(fused_gemm_apply, dim3(2304), dim3(512), 0, stream,
                       A_bf, Bm_bf, x, out);
}